// Round 6
// baseline (132.074 us; speedup 1.0000x reference)
//
#include <hip/hip_runtime.h>
#include <hip/hip_bf16.h>

#define NPIX 4096

typedef __attribute__((ext_vector_type(16))) float f32x16;
typedef __attribute__((ext_vector_type(8))) short short8;

__device__ inline short f2bf(float f) {   // round-to-nearest-even
  unsigned u = __float_as_uint(f);
  u += 0x7FFF + ((u >> 16) & 1);
  return (short)(u >> 16);
}

__device__ inline void gload16(const short* g, short* l) {
  __builtin_amdgcn_global_load_lds(
      (const __attribute__((address_space(1))) void*)g,
      (__attribute__((address_space(3))) void*)l, 16, 0, 0);
}

// ---------------- projection: 3 passes over x ----------------
// grid = 3 jobs x 128 blocks x 128 thr (thread = 1 pixel, xv[64] in regs).
// job 0: Q(8, xlog2e)+K(8) -> Qp/Kp[B*N][8] bf16
// job 1: V ch 0-31 ; job 2: V ch 32-63 -> Vi[b][oct][e][ko] (oct=n>>3, ko=n&7)
__global__ __launch_bounds__(128) void proj_kernel(
    const float* __restrict__ x,
    const float* __restrict__ Wq, const float* __restrict__ bq,
    const float* __restrict__ Wk, const float* __restrict__ bk,
    const float* __restrict__ Wv, const float* __restrict__ bv,
    short* __restrict__ Qp, short* __restrict__ Kp, short* __restrict__ Vi)
{
  const int job = blockIdx.x >> 7;
  const int p = (blockIdx.x & 127) * 128 + threadIdx.x;   // 0..16383
  const int b = p >> 12, n = p & 4095;
  const float* xb = x + ((size_t)b << 18) + n;

  float xv[64];
#pragma unroll
  for (int c = 0; c < 64; ++c) xv[c] = xb[(size_t)c << 12];

  if (job == 0) {
    float qa[8], ka[8];
#pragma unroll
    for (int d = 0; d < 8; ++d) {
      float aq = bq[d], ak = bk[d];
#pragma unroll
      for (int c = 0; c < 64; ++c) {
        aq = fmaf(Wq[d * 64 + c], xv[c], aq);   // uniform -> s_load
        ak = fmaf(Wk[d * 64 + c], xv[c], ak);
      }
      qa[d] = aq; ka[d] = ak;
    }
    short8 qo, ko;
#pragma unroll
    for (int d = 0; d < 8; ++d) {
      qo[d] = f2bf(qa[d] * 1.44269504f);        // fold log2(e) into Q
      ko[d] = f2bf(ka[d]);
    }
    *(short8*)(Qp + (size_t)p * 8) = qo;
    *(short8*)(Kp + (size_t)p * 8) = ko;
  } else {
    const int e0 = (job - 1) * 32;
    float a[32];
#pragma unroll
    for (int i = 0; i < 32; ++i) {
      float acc = bv[e0 + i];
#pragma unroll
      for (int c = 0; c < 64; ++c) acc = fmaf(Wv[(e0 + i) * 64 + c], xv[c], acc);
      a[i] = acc;
    }
    const size_t base = ((size_t)(b * 512 + (n >> 3)) * 64) * 8 + (n & 7);
#pragma unroll
    for (int i = 0; i < 32; ++i) Vi[base + (size_t)(e0 + i) * 8] = f2bf(a[i]);
  }
}

// T12 pack: 16 f32 weights -> two PV A-fragments (cvt_pk + permlane32_swap)
__device__ inline void pk_swap(const float* p, short8& A0, short8& A1) {
  unsigned u[8];
#pragma unroll
  for (int j = 0; j < 8; ++j)
    asm("v_cvt_pk_bf16_f32 %0, %1, %2" : "=v"(u[j]) : "v"(p[2 * j]), "v"(p[2 * j + 1]));
  asm("v_permlane32_swap_b32 %0, %1" : "+v"(u[0]), "+v"(u[2]));
  asm("v_permlane32_swap_b32 %0, %1" : "+v"(u[1]), "+v"(u[3]));
  asm("v_permlane32_swap_b32 %0, %1" : "+v"(u[4]), "+v"(u[6]));
  asm("v_permlane32_swap_b32 %0, %1" : "+v"(u[5]), "+v"(u[7]));
  union { unsigned w[4]; short8 s; } c0, c1;
  c0.w[0] = u[0]; c0.w[1] = u[1]; c0.w[2] = u[2]; c0.w[3] = u[3];
  c1.w[0] = u[4]; c1.w[1] = u[5]; c1.w[2] = u[6]; c1.w[3] = u[7];
  A0 = c0.s; A1 = c1.s;
}

// ---------------- attention pass 1 ----------------
// grid 256 = (4 b) x (16 qg) x (4 ks); block = 8 waves.
// Wave (qs=wv>>1, ks2=wv&1): TWO 32-q tiles (64 q at qg*256+qs*64) over the
// 512-key half ks2 of the block's 1024-key range — each 5-ds_read set now
// feeds 2x the MFMA work vs R5 (LDS-read traffic halved).
// Chunks of 128 keys double-buffered per half; staged via global_load_lds.
__global__ __launch_bounds__(512) void attn_kernel(
    const short* __restrict__ Qp, const short* __restrict__ Kp,
    const short* __restrict__ Vi,
    short* __restrict__ accB, float* __restrict__ psumW)
{
  __shared__ short kLds[2][2][1024];     // [dbuf][half][128 keys][8 ch]   8 KB
  __shared__ short vLds[2][2][8192];     // [dbuf][half][16 oct][64 e][8] 64 KB

  const int tid  = threadIdx.x;
  const int wv   = tid >> 6;
  const int qs   = wv >> 1;
  const int ks2  = wv & 1;
  const int lane = tid & 63;
  const int lo   = lane & 31;
  const int hi   = lane >> 5;

  const int bid = blockIdx.x;
  const int ks  = bid & 3;
  const int qg  = (bid >> 2) & 15;
  const int b   = bid >> 6;
  const int Qt  = (b << 12) + qg * 256 + qs * 64;     // global q of tile 0
  const int slot = ks * 2 + ks2;

  short8 qf0 = {}, qf1 = {};
  if (hi == 0) {
    qf0 = *(const short8*)(Qp + (size_t)(Qt + lo) * 8);
    qf1 = *(const short8*)(Qp + (size_t)(Qt + 32 + lo) * 8);
  }

  const short* ksrc = Kp + ((size_t)(b << 12) + ks * 1024) * 8;
  const short* vsrc = Vi + (size_t)b * 262144 + (size_t)ks * 65536;

  auto stage = [&](int s, int buf) {
#pragma unroll
    for (int h = 0; h < 2; ++h) {
      const short* vs = vsrc + (size_t)(h * 4 + s) * 8192;
      gload16(vs + (size_t)tid * 8,         &vLds[buf][h][(tid & ~63) * 8]);
      gload16(vs + (size_t)(tid + 512) * 8, &vLds[buf][h][((tid + 512) & ~63) * 8]);
    }
    if (tid < 256) {
      const int h = tid >> 7, t = tid & 127;
      gload16(ksrc + (size_t)(h * 4 + s) * 1024 + (size_t)t * 8,
              &kLds[buf][h][(t & ~63) * 8]);
    }
  };

  f32x16 acc00 = {}, acc01 = {}, acc10 = {}, acc11 = {};
  float psum0 = 0.f, psum1 = 0.f;
  const f32x16 z = {};

  stage(0, 0);
  __syncthreads();

  for (int s = 0; s < 4; ++s) {
    if (s < 3) stage(s + 1, (s + 1) & 1);
    const int buf = s & 1;
    const short* kbuf = &kLds[buf][ks2][0];
    const short* vbuf = &vLds[buf][ks2][0];
#pragma unroll
    for (int i = 0; i < 4; ++i) {
      short8 kf = *(const short8*)&kbuf[(i * 32 + lo) * 8];
      short8 v00 = *(const short8*)&vbuf[(i * 4 + hi) * 512 + lo * 8];
      short8 v01 = *(const short8*)&vbuf[(i * 4 + hi) * 512 + (32 + lo) * 8];
      short8 v10 = *(const short8*)&vbuf[(i * 4 + 2 + hi) * 512 + lo * 8];
      short8 v11 = *(const short8*)&vbuf[(i * 4 + 2 + hi) * 512 + (32 + lo) * 8];

      f32x16 en = __builtin_amdgcn_mfma_f32_32x32x16_bf16(kf, qf0, z, 0, 0, 0);
      float p[16];
#pragma unroll
      for (int j = 0; j < 16; ++j) p[j] = __builtin_amdgcn_exp2f(en[j]);
#pragma unroll
      for (int j = 0; j < 16; ++j) psum0 += p[j];
      short8 a0, a1;
      pk_swap(p, a0, a1);
      __builtin_amdgcn_s_setprio(1);
      acc00 = __builtin_amdgcn_mfma_f32_32x32x16_bf16(a0, v00, acc00, 0, 0, 0);
      acc01 = __builtin_amdgcn_mfma_f32_32x32x16_bf16(a0, v01, acc01, 0, 0, 0);
      acc00 = __builtin_amdgcn_mfma_f32_32x32x16_bf16(a1, v10, acc00, 0, 0, 0);
      acc01 = __builtin_amdgcn_mfma_f32_32x32x16_bf16(a1, v11, acc01, 0, 0, 0);
      __builtin_amdgcn_s_setprio(0);

      en = __builtin_amdgcn_mfma_f32_32x32x16_bf16(kf, qf1, z, 0, 0, 0);
#pragma unroll
      for (int j = 0; j < 16; ++j) p[j] = __builtin_amdgcn_exp2f(en[j]);
#pragma unroll
      for (int j = 0; j < 16; ++j) psum1 += p[j];
      short8 b0, b1;
      pk_swap(p, b0, b1);
      __builtin_amdgcn_s_setprio(1);
      acc10 = __builtin_amdgcn_mfma_f32_32x32x16_bf16(b0, v00, acc10, 0, 0, 0);
      acc11 = __builtin_amdgcn_mfma_f32_32x32x16_bf16(b0, v01, acc11, 0, 0, 0);
      acc10 = __builtin_amdgcn_mfma_f32_32x32x16_bf16(b1, v10, acc10, 0, 0, 0);
      acc11 = __builtin_amdgcn_mfma_f32_32x32x16_bf16(b1, v11, acc11, 0, 0, 0);
      __builtin_amdgcn_s_setprio(0);
    }
    __syncthreads();   // drains staging vmcnt; readers done before overwrite
  }

  // psum partials (sum the two hi-halves; lane lo holds q of its tile)
  float pf0 = psum0 + __shfl_xor(psum0, 32);
  float pf1 = psum1 + __shfl_xor(psum1, 32);
  if (hi == 0) {
    psumW[slot * 16384 + Qt + lo]      = pf0;
    psumW[slot * 16384 + Qt + 32 + lo] = pf1;
  }

  // O partials: bf16 [slot][gq][64 e]
#pragma unroll
  for (int r = 0; r < 16; ++r) {
    const int q = (r & 3) + 8 * (r >> 2) + 4 * hi;   // D-layout row
    const size_t b0i = ((size_t)(slot * 16384 + Qt + q)) << 6;
    const size_t b1i = ((size_t)(slot * 16384 + Qt + 32 + q)) << 6;
    accB[b0i + lo]      = f2bf(acc00[r]);
    accB[b0i + 32 + lo] = f2bf(acc01[r]);
    accB[b1i + lo]      = f2bf(acc10[r]);
    accB[b1i + 32 + lo] = f2bf(acc11[r]);
  }
}

// ---------------- attention pass 2: combine 8 key-splits + epilogue ----------------
__global__ __launch_bounds__(256) void reduce_kernel(
    const short* __restrict__ accB, const float* __restrict__ psumW,
    const float* __restrict__ x, const float* __restrict__ gamma,
    float* __restrict__ out)
{
  __shared__ float accLds[64][65];
  __shared__ float sInv[64];

  const int tid = threadIdx.x;
  const int Qg0 = blockIdx.x * 64;
  const float g = gamma[0];

  if (tid < 64) {
    float s = 0.f;
#pragma unroll
    for (int sl = 0; sl < 8; ++sl) s += psumW[sl * 16384 + Qg0 + tid];
    sInv[tid] = g / s;
  }

  const int e2 = tid & 31;          // e-pair index
  const int qr = tid >> 5;
#pragma unroll
  for (int qsw = 0; qsw < 8; ++qsw) {
    const int qq = qr + qsw * 8;
    float s0 = 0.f, s1 = 0.f;
#pragma unroll
    for (int sl = 0; sl < 8; ++sl) {
      const unsigned u = *(const unsigned*)&accB[(((size_t)(sl * 16384 + Qg0 + qq)) << 6) + e2 * 2];
      s0 += __uint_as_float(u << 16);
      s1 += __uint_as_float(u & 0xFFFF0000u);
    }
    accLds[qq][e2 * 2]     = s0;
    accLds[qq][e2 * 2 + 1] = s1;
  }
  __syncthreads();

  const int q  = tid & 63;
  const int er = tid >> 6;
  const int b  = (Qg0 + q) >> 12;
  const int n  = (Qg0 + q) & 4095;
  const float si = sInv[q];
#pragma unroll
  for (int k = 0; k < 16; ++k) {
    const int e = er + k * 4;
    const size_t idx = ((size_t)(b * 64 + e) << 12) + n;
    out[idx] = fmaf(si, accLds[q][e], x[idx]);
  }
}

extern "C" void kernel_launch(void* const* d_in, const int* in_sizes, int n_in,
                              void* d_out, int out_size, void* d_ws, size_t ws_size,
                              hipStream_t stream) {
  const float* x     = (const float*)d_in[0];
  const float* Wq    = (const float*)d_in[1];
  const float* bq    = (const float*)d_in[2];
  const float* Wk    = (const float*)d_in[3];
  const float* bk    = (const float*)d_in[4];
  const float* Wv    = (const float*)d_in[5];
  const float* bv    = (const float*)d_in[6];
  const float* gamma = (const float*)d_in[7];
  float* out = (float*)d_out;

  short* ws    = (short*)d_ws;
  short* Qp    = ws;                       // 131072 shorts
  short* Kp    = ws + 131072;              // 131072 shorts
  short* Vi    = ws + 262144;              // 1048576 shorts: [4][512][64][8]
  short* accB  = ws + 1310720;             // 8*16384*64 shorts = 16 MB
  float* psumW = (float*)(ws + 9699328);   // 8*16384 floats = 512 KB

  proj_kernel<<<384, 128, 0, stream>>>(x, Wq, bq, Wk, bk, Wv, bv, Qp, Kp, Vi);
  attn_kernel<<<256, 512, 0, stream>>>(Qp, Kp, Vi, accB, psumW);
  reduce_kernel<<<256, 256, 0, stream>>>(accB, psumW, x, gamma, out);
}

// Round 7
// 117.046 us; speedup vs baseline: 1.1284x; 1.1284x over previous
//
#include <hip/hip_runtime.h>
#include <hip/hip_bf16.h>

#define NPIX 4096

typedef __attribute__((ext_vector_type(16))) float f32x16;
typedef __attribute__((ext_vector_type(8))) short short8;

__device__ inline short f2bf(float f) {   // round-to-nearest-even
  unsigned u = __float_as_uint(f);
  u += 0x7FFF + ((u >> 16) & 1);
  return (short)(u >> 16);
}

__device__ inline void gload16(const short* g, short* l) {
  __builtin_amdgcn_global_load_lds(
      (const __attribute__((address_space(1))) void*)g,
      (__attribute__((address_space(3))) void*)l, 16, 0, 0);
}

// ---------------- projection: 5 jobs x 16 outputs, chunked x ----------------
// grid = 5 jobs x 64 blocks x 256 thr (thread = 1 pixel).
// job 0: Q(8, xlog2e)+K(8) -> Qp/Kp[B*N][8]
// jobs 1-4: V ch 16*(job-1)..+16 -> Vi[b][oct][e][ko] (oct=n>>3, ko=n&7)
// xv chunked 16-at-a-time: ~50 VGPR -> high occupancy; x traffic = 5 passes.
__global__ __launch_bounds__(256) void proj_kernel(
    const float* __restrict__ x,
    const float* __restrict__ Wq, const float* __restrict__ bq,
    const float* __restrict__ Wk, const float* __restrict__ bk,
    const float* __restrict__ Wv, const float* __restrict__ bv,
    short* __restrict__ Qp, short* __restrict__ Kp, short* __restrict__ Vi)
{
  const int job = blockIdx.x >> 6;
  const int p = (blockIdx.x & 63) * 256 + threadIdx.x;   // 0..16383
  const int b = p >> 12, n = p & 4095;
  const float* xb = x + ((size_t)b << 18) + n;

  if (job == 0) {
    float qa[8], ka[8];
#pragma unroll
    for (int d = 0; d < 8; ++d) { qa[d] = bq[d]; ka[d] = bk[d]; }
    for (int c0 = 0; c0 < 64; c0 += 16) {
      float xv[16];
#pragma unroll
      for (int i = 0; i < 16; ++i) xv[i] = xb[(size_t)(c0 + i) << 12];
#pragma unroll
      for (int d = 0; d < 8; ++d) {
#pragma unroll
        for (int i = 0; i < 16; ++i) {
          qa[d] = fmaf(Wq[d * 64 + c0 + i], xv[i], qa[d]);   // uniform -> s_load
          ka[d] = fmaf(Wk[d * 64 + c0 + i], xv[i], ka[d]);
        }
      }
    }
    short8 qo, ko;
#pragma unroll
    for (int d = 0; d < 8; ++d) {
      qo[d] = f2bf(qa[d] * 1.44269504f);        // fold log2(e) into Q
      ko[d] = f2bf(ka[d]);
    }
    *(short8*)(Qp + (size_t)p * 8) = qo;
    *(short8*)(Kp + (size_t)p * 8) = ko;
  } else {
    const int e0 = (job - 1) * 16;
    float a[16];
#pragma unroll
    for (int i = 0; i < 16; ++i) a[i] = bv[e0 + i];
    for (int c0 = 0; c0 < 64; c0 += 16) {
      float xv[16];
#pragma unroll
      for (int i = 0; i < 16; ++i) xv[i] = xb[(size_t)(c0 + i) << 12];
#pragma unroll
      for (int i = 0; i < 16; ++i) {
#pragma unroll
        for (int c = 0; c < 16; ++c)
          a[i] = fmaf(Wv[(e0 + i) * 64 + c0 + c], xv[c], a[i]);
      }
    }
    const size_t base = ((size_t)(b * 512 + (n >> 3)) * 64) * 8 + (n & 7);
#pragma unroll
    for (int i = 0; i < 16; ++i) Vi[base + (size_t)(e0 + i) * 8] = f2bf(a[i]);
  }
}

// T12 pack: 16 f32 weights -> two PV A-fragments (cvt_pk + permlane32_swap)
__device__ inline void pk_swap(const float* p, short8& A0, short8& A1) {
  unsigned u[8];
#pragma unroll
  for (int j = 0; j < 8; ++j)
    asm("v_cvt_pk_bf16_f32 %0, %1, %2" : "=v"(u[j]) : "v"(p[2 * j]), "v"(p[2 * j + 1]));
  asm("v_permlane32_swap_b32 %0, %1" : "+v"(u[0]), "+v"(u[2]));
  asm("v_permlane32_swap_b32 %0, %1" : "+v"(u[1]), "+v"(u[3]));
  asm("v_permlane32_swap_b32 %0, %1" : "+v"(u[4]), "+v"(u[6]));
  asm("v_permlane32_swap_b32 %0, %1" : "+v"(u[5]), "+v"(u[7]));
  union { unsigned w[4]; short8 s; } c0, c1;
  c0.w[0] = u[0]; c0.w[1] = u[1]; c0.w[2] = u[2]; c0.w[3] = u[3];
  c1.w[0] = u[4]; c1.w[1] = u[5]; c1.w[2] = u[6]; c1.w[3] = u[7];
  A0 = c0.s; A1 = c1.s;
}

// ---------------- attention pass 1 ----------------
// grid 512 = (4 b) x (16 qg) x (8 ks); block = 4 waves (256 thr) -> 2 blocks/CU.
// Wave wv owns TWO 32-q tiles (64 q at qg*256 + wv*64) over the block's
// 512-key range [ks*512,+512), in 4 chunks of 128 keys, double-buffered in
// 36 KB LDS staged via global_load_lds (same per-MFMA ds_read cost as R6's
// two-tile scheme, but at R5's LDS footprint and 2x R5's resident blocks).
__global__ __launch_bounds__(256) void attn_kernel(
    const short* __restrict__ Qp, const short* __restrict__ Kp,
    const short* __restrict__ Vi,
    short* __restrict__ accB, float* __restrict__ psumW)
{
  __shared__ short kLds[2][1024];        // [dbuf][128 keys][8 ch]    4 KB
  __shared__ short vLds[2][8192];        // [dbuf][16 oct][64 e][8 k] 32 KB

  const int tid  = threadIdx.x;
  const int wv   = tid >> 6;
  const int lane = tid & 63;
  const int lo   = lane & 31;
  const int hi   = lane >> 5;

  const int bid = blockIdx.x;
  const int ks  = bid & 7;
  const int qg  = (bid >> 3) & 15;
  const int b   = bid >> 7;
  const int Qt  = (b << 12) + qg * 256 + wv * 64;     // global q of tile 0
  const int slot = ks;

  short8 qf0 = {}, qf1 = {};
  if (hi == 0) {
    qf0 = *(const short8*)(Qp + (size_t)(Qt + lo) * 8);
    qf1 = *(const short8*)(Qp + (size_t)(Qt + 32 + lo) * 8);
  }

  const short* ksrc = Kp + ((size_t)(b << 12) + ks * 512) * 8;
  const short* vsrc = Vi + (size_t)b * 262144 + (size_t)ks * 32768;

  auto stage = [&](int c, int buf) {
    const short* vs = vsrc + (size_t)c * 8192;
#pragma unroll
    for (int j = 0; j < 4; ++j)
      gload16(vs + (size_t)(tid + j * 256) * 8,
              &vLds[buf][((tid + j * 256) & ~63) * 8]);
    if (tid < 128)
      gload16(ksrc + (size_t)c * 1024 + (size_t)tid * 8,
              &kLds[buf][(tid & ~63) * 8]);
  };

  f32x16 acc00 = {}, acc01 = {}, acc10 = {}, acc11 = {};
  float psum0 = 0.f, psum1 = 0.f;
  const f32x16 z = {};

  stage(0, 0);
  __syncthreads();

  for (int s = 0; s < 4; ++s) {
    if (s < 3) stage(s + 1, (s + 1) & 1);
    const int buf = s & 1;
    const short* kbuf = &kLds[buf][0];
    const short* vbuf = &vLds[buf][0];
#pragma unroll
    for (int i = 0; i < 4; ++i) {
      short8 kf = *(const short8*)&kbuf[(i * 32 + lo) * 8];
      short8 v00 = *(const short8*)&vbuf[(i * 4 + hi) * 512 + lo * 8];
      short8 v01 = *(const short8*)&vbuf[(i * 4 + hi) * 512 + (32 + lo) * 8];
      short8 v10 = *(const short8*)&vbuf[(i * 4 + 2 + hi) * 512 + lo * 8];
      short8 v11 = *(const short8*)&vbuf[(i * 4 + 2 + hi) * 512 + (32 + lo) * 8];

      f32x16 en = __builtin_amdgcn_mfma_f32_32x32x16_bf16(kf, qf0, z, 0, 0, 0);
      float p[16];
#pragma unroll
      for (int j = 0; j < 16; ++j) p[j] = __builtin_amdgcn_exp2f(en[j]);
#pragma unroll
      for (int j = 0; j < 16; ++j) psum0 += p[j];
      short8 a0, a1;
      pk_swap(p, a0, a1);
      __builtin_amdgcn_s_setprio(1);
      acc00 = __builtin_amdgcn_mfma_f32_32x32x16_bf16(a0, v00, acc00, 0, 0, 0);
      acc01 = __builtin_amdgcn_mfma_f32_32x32x16_bf16(a0, v01, acc01, 0, 0, 0);
      acc00 = __builtin_amdgcn_mfma_f32_32x32x16_bf16(a1, v10, acc00, 0, 0, 0);
      acc01 = __builtin_amdgcn_mfma_f32_32x32x16_bf16(a1, v11, acc01, 0, 0, 0);
      __builtin_amdgcn_s_setprio(0);

      en = __builtin_amdgcn_mfma_f32_32x32x16_bf16(kf, qf1, z, 0, 0, 0);
#pragma unroll
      for (int j = 0; j < 16; ++j) p[j] = __builtin_amdgcn_exp2f(en[j]);
#pragma unroll
      for (int j = 0; j < 16; ++j) psum1 += p[j];
      short8 b0, b1;
      pk_swap(p, b0, b1);
      __builtin_amdgcn_s_setprio(1);
      acc10 = __builtin_amdgcn_mfma_f32_32x32x16_bf16(b0, v00, acc10, 0, 0, 0);
      acc11 = __builtin_amdgcn_mfma_f32_32x32x16_bf16(b0, v01, acc11, 0, 0, 0);
      acc10 = __builtin_amdgcn_mfma_f32_32x32x16_bf16(b1, v10, acc10, 0, 0, 0);
      acc11 = __builtin_amdgcn_mfma_f32_32x32x16_bf16(b1, v11, acc11, 0, 0, 0);
      __builtin_amdgcn_s_setprio(0);
    }
    __syncthreads();   // drains staging vmcnt; readers done before overwrite
  }

  // psum partials (combine hi halves; lane lo holds q of its tile)
  float pf0 = psum0 + __shfl_xor(psum0, 32);
  float pf1 = psum1 + __shfl_xor(psum1, 32);
  if (hi == 0) {
    psumW[slot * 16384 + Qt + lo]      = pf0;
    psumW[slot * 16384 + Qt + 32 + lo] = pf1;
  }

  // O partials: bf16 [slot][gq][64 e]
#pragma unroll
  for (int r = 0; r < 16; ++r) {
    const int q = (r & 3) + 8 * (r >> 2) + 4 * hi;   // D-layout row
    const size_t b0i = ((size_t)(slot * 16384 + Qt + q)) << 6;
    const size_t b1i = ((size_t)(slot * 16384 + Qt + 32 + q)) << 6;
    accB[b0i + lo]      = f2bf(acc00[r]);
    accB[b0i + 32 + lo] = f2bf(acc01[r]);
    accB[b1i + lo]      = f2bf(acc10[r]);
    accB[b1i + 32 + lo] = f2bf(acc11[r]);
  }
}

// ---------------- attention pass 2: combine 8 key-splits + epilogue ----------------
__global__ __launch_bounds__(256) void reduce_kernel(
    const short* __restrict__ accB, const float* __restrict__ psumW,
    const float* __restrict__ x, const float* __restrict__ gamma,
    float* __restrict__ out)
{
  __shared__ float accLds[64][65];
  __shared__ float sInv[64];

  const int tid = threadIdx.x;
  const int Qg0 = blockIdx.x * 64;
  const float g = gamma[0];

  if (tid < 64) {
    float s = 0.f;
#pragma unroll
    for (int sl = 0; sl < 8; ++sl) s += psumW[sl * 16384 + Qg0 + tid];
    sInv[tid] = g / s;
  }

  const int e2 = tid & 31;          // e-pair index
  const int qr = tid >> 5;
#pragma unroll
  for (int qsw = 0; qsw < 8; ++qsw) {
    const int qq = qr + qsw * 8;
    float s0 = 0.f, s1 = 0.f;
#pragma unroll
    for (int sl = 0; sl < 8; ++sl) {
      const unsigned u = *(const unsigned*)&accB[(((size_t)(sl * 16384 + Qg0 + qq)) << 6) + e2 * 2];
      s0 += __uint_as_float(u << 16);
      s1 += __uint_as_float(u & 0xFFFF0000u);
    }
    accLds[qq][e2 * 2]     = s0;
    accLds[qq][e2 * 2 + 1] = s1;
  }
  __syncthreads();

  const int q  = tid & 63;
  const int er = tid >> 6;
  const int b  = (Qg0 + q) >> 12;
  const int n  = (Qg0 + q) & 4095;
  const float si = sInv[q];
#pragma unroll
  for (int k = 0; k < 16; ++k) {
    const int e = er + k * 4;
    const size_t idx = ((size_t)(b * 64 + e) << 12) + n;
    out[idx] = fmaf(si, accLds[q][e], x[idx]);
  }
}

extern "C" void kernel_launch(void* const* d_in, const int* in_sizes, int n_in,
                              void* d_out, int out_size, void* d_ws, size_t ws_size,
                              hipStream_t stream) {
  const float* x     = (const float*)d_in[0];
  const float* Wq    = (const float*)d_in[1];
  const float* bq    = (const float*)d_in[2];
  const float* Wk    = (const float*)d_in[3];
  const float* bk    = (const float*)d_in[4];
  const float* Wv    = (const float*)d_in[5];
  const float* bv    = (const float*)d_in[6];
  const float* gamma = (const float*)d_in[7];
  float* out = (float*)d_out;

  short* ws    = (short*)d_ws;
  short* Qp    = ws;                       // 131072 shorts
  short* Kp    = ws + 131072;              // 131072 shorts
  short* Vi    = ws + 262144;              // 1048576 shorts: [4][512][64][8]
  short* accB  = ws + 1310720;             // 8*16384*64 shorts = 16 MB
  float* psumW = (float*)(ws + 9699328);   // 8*16384 floats = 512 KB

  proj_kernel<<<320, 256, 0, stream>>>(x, Wq, bq, Wk, bk, Wv, bv, Qp, Kp, Vi);
  attn_kernel<<<512, 256, 0, stream>>>(Qp, Kp, Vi, accB, psumW);
  reduce_kernel<<<256, 256, 0, stream>>>(accB, psumW, x, gamma, out);
}

// Round 9
// 107.794 us; speedup vs baseline: 1.2252x; 1.0858x over previous
//
#include <hip/hip_runtime.h>
#include <hip/hip_bf16.h>

#define NPIX 4096

typedef __attribute__((ext_vector_type(16))) float f32x16;
typedef __attribute__((ext_vector_type(8))) short short8;

__device__ inline short f2bf(float f) {   // round-to-nearest-even
  unsigned u = __float_as_uint(f);
  u += 0x7FFF + ((u >> 16) & 1);
  return (short)(u >> 16);
}

__device__ inline void gload16(const short* g, short* l) {
  __builtin_amdgcn_global_load_lds(
      (const __attribute__((address_space(1))) void*)g,
      (__attribute__((address_space(3))) void*)l, 16, 0, 0);
}

// ---------------- projection (R5-proven 10-pass layout) ----------------
// grid = 10 jobs x 64 blocks x 256 thr; thread = 1 pixel, 8 outputs.
// Occupancy (2560 waves) beats x re-reads (x is 4MB, L3-resident).
// job 0: Q rows (xlog2e) -> Qp[B*N][8]; job 1: K -> Kp[B*N][8];
// jobs 2-9: V ch 8*(job-2)..+8 -> Vi[b][oct][e][ko] (oct=n>>3, ko=n&7)
__global__ __launch_bounds__(256) void proj_kernel(
    const float* __restrict__ x,
    const float* __restrict__ Wq, const float* __restrict__ bq,
    const float* __restrict__ Wk, const float* __restrict__ bk,
    const float* __restrict__ Wv, const float* __restrict__ bv,
    short* __restrict__ Qp, short* __restrict__ Kp, short* __restrict__ Vi)
{
  const int job = blockIdx.x >> 6;
  const int p = (blockIdx.x & 63) * 256 + threadIdx.x;
  const int b = p >> 12, n = p & 4095;
  const float* xb = x + ((size_t)b << 18) + n;

  float xv[64];
#pragma unroll
  for (int c = 0; c < 64; ++c) xv[c] = xb[(size_t)c << 12];

  if (job < 2) {
    const float* W    = job ? Wk : Wq;
    const float* bias = job ? bk : bq;
    float a[8];
#pragma unroll
    for (int d = 0; d < 8; ++d) {
      float acc = bias[d];
#pragma unroll
      for (int c = 0; c < 64; ++c) acc = fmaf(W[d * 64 + c], xv[c], acc);
      a[d] = acc;
    }
    short8 o;
    if (job == 0) {
#pragma unroll
      for (int d = 0; d < 8; ++d) o[d] = f2bf(a[d] * 1.44269504f);  // fold log2e
      *(short8*)(Qp + (size_t)p * 8) = o;
    } else {
#pragma unroll
      for (int d = 0; d < 8; ++d) o[d] = f2bf(a[d]);
      *(short8*)(Kp + (size_t)p * 8) = o;
    }
  } else {
    const int e0 = (job - 2) * 8;
    const size_t base = ((size_t)(b * 512 + (n >> 3)) * 64) * 8 + (n & 7);
#pragma unroll
    for (int i = 0; i < 8; ++i) {
      float acc = bv[e0 + i];
#pragma unroll
      for (int c = 0; c < 64; ++c) acc = fmaf(Wv[(e0 + i) * 64 + c], xv[c], acc);
      Vi[base + (size_t)(e0 + i) * 8] = f2bf(acc);
    }
  }
}

// T12 pack: 16 f32 weights -> two PV A-fragments (cvt_pk + permlane32_swap)
__device__ inline void pk_swap(const float* p, short8& A0, short8& A1) {
  unsigned u[8];
#pragma unroll
  for (int j = 0; j < 8; ++j)
    asm("v_cvt_pk_bf16_f32 %0, %1, %2" : "=v"(u[j]) : "v"(p[2 * j]), "v"(p[2 * j + 1]));
  asm("v_permlane32_swap_b32 %0, %1" : "+v"(u[0]), "+v"(u[2]));
  asm("v_permlane32_swap_b32 %0, %1" : "+v"(u[1]), "+v"(u[3]));
  asm("v_permlane32_swap_b32 %0, %1" : "+v"(u[4]), "+v"(u[6]));
  asm("v_permlane32_swap_b32 %0, %1" : "+v"(u[5]), "+v"(u[7]));
  union { unsigned w[4]; short8 s; } c0, c1;
  c0.w[0] = u[0]; c0.w[1] = u[1]; c0.w[2] = u[2]; c0.w[3] = u[3];
  c1.w[0] = u[4]; c1.w[1] = u[5]; c1.w[2] = u[6]; c1.w[3] = u[7];
  A0 = c0.s; A1 = c1.s;
}

// ---------------- attention pass 1 (R5 structure, 8 key-splits) ----------------
// grid 512 = (4 b) x (16 qg) x (8 ks); block = 8 waves (512 thr) -> 2 blocks/CU.
// Wave wv owns the 32-q tile at qg*256 + wv*32 over keys [ks*512,+512) in
// 4 chunks of 128 keys, double-buffered 36KB LDS via global_load_lds.
// Same LDS-sharing ratio and staged bytes as R5, but 2x resident blocks.
__global__ __launch_bounds__(512, 2) void attn_kernel(
    const short* __restrict__ Qp, const short* __restrict__ Kp,
    const short* __restrict__ Vi,
    short* __restrict__ accB, float* __restrict__ psumW)
{
  __shared__ short kLds[2][1024];        // [dbuf][128 keys][8 ch]    4 KB
  __shared__ short vLds[2][8192];        // [dbuf][16 oct][64 e][8 k] 32 KB

  const int tid  = threadIdx.x;
  const int wv   = tid >> 6;
  const int lane = tid & 63;
  const int lo   = lane & 31;
  const int hi   = lane >> 5;

  const int bid = blockIdx.x;
  const int ks  = bid & 7;
  const int qg  = (bid >> 3) & 15;
  const int b   = bid >> 7;
  const int Qgbase = (b << 12) + qg * 256 + wv * 32;   // global q base of the wave
  const int slot = ks;

  short8 qf = {};
  if (hi == 0) qf = *(const short8*)(Qp + (size_t)(Qgbase + lo) * 8);

  const short* ksrc = Kp + ((size_t)(b << 12) + ks * 512) * 8;
  const short* vsrc = Vi + (size_t)b * 262144 + (size_t)ks * 32768;

  auto stage = [&](int c, int buf) {
    const short* vs = vsrc + (size_t)c * 8192;
    gload16(vs + (size_t)tid * 8,         &vLds[buf][(tid & ~63) * 8]);
    gload16(vs + (size_t)(tid + 512) * 8, &vLds[buf][((tid + 512) & ~63) * 8]);
    if (tid < 128)
      gload16(ksrc + (size_t)c * 1024 + (size_t)tid * 8, &kLds[buf][(tid & ~63) * 8]);
  };

  f32x16 acc0 = {}, acc1 = {};
  float psum = 0.f;
  const f32x16 z = {};

  stage(0, 0);
  __syncthreads();

  for (int c = 0; c < 4; ++c) {
    if (c < 3) stage(c + 1, (c + 1) & 1);
    const int buf = c & 1;
#pragma unroll
    for (int i = 0; i < 4; ++i) {
      short8 kf = *(const short8*)&kLds[buf][(i * 32 + lo) * 8];
      f32x16 en = __builtin_amdgcn_mfma_f32_32x32x16_bf16(kf, qf, z, 0, 0, 0);
      float p[16];
#pragma unroll
      for (int j = 0; j < 16; ++j) p[j] = __builtin_amdgcn_exp2f(en[j]);
#pragma unroll
      for (int j = 0; j < 16; ++j) psum += p[j];
      short8 a0, a1;
      pk_swap(p, a0, a1);
      short8 v00 = *(const short8*)&vLds[buf][(i * 4 + hi) * 512 + lo * 8];
      short8 v01 = *(const short8*)&vLds[buf][(i * 4 + hi) * 512 + (32 + lo) * 8];
      short8 v10 = *(const short8*)&vLds[buf][(i * 4 + 2 + hi) * 512 + lo * 8];
      short8 v11 = *(const short8*)&vLds[buf][(i * 4 + 2 + hi) * 512 + (32 + lo) * 8];
      __builtin_amdgcn_s_setprio(1);
      acc0 = __builtin_amdgcn_mfma_f32_32x32x16_bf16(a0, v00, acc0, 0, 0, 0);
      acc1 = __builtin_amdgcn_mfma_f32_32x32x16_bf16(a0, v01, acc1, 0, 0, 0);
      acc0 = __builtin_amdgcn_mfma_f32_32x32x16_bf16(a1, v10, acc0, 0, 0, 0);
      acc1 = __builtin_amdgcn_mfma_f32_32x32x16_bf16(a1, v11, acc1, 0, 0, 0);
      __builtin_amdgcn_s_setprio(0);
    }
    __syncthreads();   // drains staging vmcnt; readers done before overwrite
  }

  // partial psum: combine hi halves, store per q (coalesced)
  float pfull = psum + __shfl_xor(psum, 32);
  if (hi == 0) psumW[slot * 16384 + Qgbase + lo] = pfull;

  // partial O: bf16 [slot][gq][64 e]
#pragma unroll
  for (int r = 0; r < 16; ++r) {
    const int q = (r & 3) + 8 * (r >> 2) + 4 * hi;   // D-layout row
    const size_t base = ((size_t)(slot * 16384 + Qgbase + q)) << 6;
    accB[base + lo]      = f2bf(acc0[r]);
    accB[base + 32 + lo] = f2bf(acc1[r]);
  }
}

// ---------------- attention pass 2: combine 8 key-splits + epilogue ----------------
__global__ __launch_bounds__(256) void reduce_kernel(
    const short* __restrict__ accB, const float* __restrict__ psumW,
    const float* __restrict__ x, const float* __restrict__ gamma,
    float* __restrict__ out)
{
  __shared__ float accLds[64][65];
  __shared__ float sInv[64];

  const int tid = threadIdx.x;
  const int Qg0 = blockIdx.x * 64;
  const float g = gamma[0];

  if (tid < 64) {
    float s = 0.f;
#pragma unroll
    for (int sl = 0; sl < 8; ++sl) s += psumW[sl * 16384 + Qg0 + tid];
    sInv[tid] = g / s;
  }

  const int e2 = tid & 31;          // e-pair index
  const int qr = tid >> 5;
#pragma unroll
  for (int qsw = 0; qsw < 8; ++qsw) {
    const int qq = qr + qsw * 8;
    float s0 = 0.f, s1 = 0.f;
#pragma unroll
    for (int sl = 0; sl < 8; ++sl) {
      const unsigned u = *(const unsigned*)&accB[(((size_t)(sl * 16384 + Qg0 + qq)) << 6) + e2 * 2];
      s0 += __uint_as_float(u << 16);
      s1 += __uint_as_float(u & 0xFFFF0000u);
    }
    accLds[qq][e2 * 2]     = s0;
    accLds[qq][e2 * 2 + 1] = s1;
  }
  __syncthreads();

  const int q  = tid & 63;
  const int er = tid >> 6;
  const int b  = (Qg0 + q) >> 12;
  const int n  = (Qg0 + q) & 4095;
  const float si = sInv[q];
#pragma unroll
  for (int k = 0; k < 16; ++k) {
    const int e = er + k * 4;
    const size_t idx = ((size_t)(b * 64 + e) << 12) + n;
    out[idx] = fmaf(si, accLds[q][e], x[idx]);
  }
}

extern "C" void kernel_launch(void* const* d_in, const int* in_sizes, int n_in,
                              void* d_out, int out_size, void* d_ws, size_t ws_size,
                              hipStream_t stream) {
  const float* x     = (const float*)d_in[0];
  const float* Wq    = (const float*)d_in[1];
  const float* bq    = (const float*)d_in[2];
  const float* Wk    = (const float*)d_in[3];
  const float* bk    = (const float*)d_in[4];
  const float* Wv    = (const float*)d_in[5];
  const float* bv    = (const float*)d_in[6];
  const float* gamma = (const float*)d_in[7];
  float* out = (float*)d_out;

  short* ws    = (short*)d_ws;
  short* Qp    = ws;                       // 131072 shorts
  short* Kp    = ws + 131072;              // 131072 shorts
  short* Vi    = ws + 262144;              // 1048576 shorts: [4][512][64][8]
  short* accB  = ws + 1310720;             // 8*16384*64 shorts = 16 MB
  float* psumW = (float*)(ws + 9699328);   // 8*16384 floats = 512 KB

  proj_kernel<<<640, 256, 0, stream>>>(x, Wq, bq, Wk, bk, Wv, bv, Qp, Kp, Vi);
  attn_kernel<<<512, 512, 0, stream>>>(Qp, Kp, Vi, accB, psumW);
  reduce_kernel<<<256, 256, 0, stream>>>(accB, psumW, x, gamma, out);
}